// Round 4
// baseline (1115.220 us; speedup 1.0000x reference)
//
#include <hip/hip_runtime.h>

typedef __attribute__((ext_vector_type(8))) __bf16 bf16x8;
typedef __attribute__((ext_vector_type(4))) float f32x4;

#define GLOAD_LDS16(g, l)                                                     \
  __builtin_amdgcn_global_load_lds(                                           \
      (const __attribute__((address_space(1))) void*)(g),                     \
      (__attribute__((address_space(3))) void*)(l), 16, 0, 0)

#define BAR() __builtin_amdgcn_s_barrier()
#define SB0() __builtin_amdgcn_sched_barrier(0)
#define LGKM(n)                                                               \
  do {                                                                        \
    asm volatile("s_waitcnt lgkmcnt(" #n ")" ::: "memory");                   \
    SB0();                                                                    \
  } while (0)
#define VMCNT0() asm volatile("s_waitcnt vmcnt(0)" ::: "memory")
#define PRIO1() __builtin_amdgcn_s_setprio(1)
#define PRIO0() __builtin_amdgcn_s_setprio(0)
#define MFMA_BF16 __builtin_amdgcn_mfma_f32_16x16x32_bf16

__device__ __forceinline__ unsigned short f32_to_bf16(float f) {
  unsigned int u = __builtin_bit_cast(unsigned int, f);
  u += 0x7FFFu + ((u >> 16) & 1u);
  return (unsigned short)(u >> 16);
}

// ---------------- f32 -> bf16 conversion ----------------------------------
__global__ void conv_f32_bf16(const float* __restrict__ in,
                              unsigned short* __restrict__ out, int n4) {
  int stride = gridDim.x * blockDim.x;
  for (int i = blockIdx.x * blockDim.x + threadIdx.x; i < n4; i += stride) {
    float4 v = reinterpret_cast<const float4*>(in)[i];
    ushort4 o;
    o.x = f32_to_bf16(v.x);
    o.y = f32_to_bf16(v.y);
    o.z = f32_to_bf16(v.z);
    o.w = f32_to_bf16(v.w);
    reinterpret_cast<ushort4*>(out)[i] = o;
  }
}

// ---------------- FWHT rows of 8192, * 1/sqrt(8192), bf16 out --------------
__global__ void fwht_rows_bf16(const float* __restrict__ in,
                               unsigned short* __restrict__ out) {
  __shared__ float s[8192];
  const int tid = threadIdx.x;  // 256 threads
  const float* row = in + (size_t)blockIdx.x * 8192;
#pragma unroll
  for (int i = 0; i < 8; ++i)
    reinterpret_cast<float4*>(s)[tid + i * 256] =
        reinterpret_cast<const float4*>(row)[tid + i * 256];
  for (int h = 1; h < 8192; h <<= 1) {
    __syncthreads();
#pragma unroll
    for (int it = 0; it < 16; ++it) {
      int i = tid + it * 256;
      int j = ((i & ~(h - 1)) << 1) | (i & (h - 1));
      float a = s[j], b = s[j + h];
      s[j] = a + b;
      s[j + h] = a - b;
    }
  }
  __syncthreads();
  const float scale = 0.011048543456039806f;  // 1/sqrt(8192)
  unsigned short* orow = out + (size_t)blockIdx.x * 8192;
#pragma unroll
  for (int i = 0; i < 8; ++i) {
    float4 v = reinterpret_cast<const float4*>(s)[tid + i * 256];
    ushort4 o;
    o.x = f32_to_bf16(v.x * scale);
    o.y = f32_to_bf16(v.y * scale);
    o.z = f32_to_bf16(v.z * scale);
    o.w = f32_to_bf16(v.w * scale);
    reinterpret_cast<ushort4*>(orow)[tid + i * 256] = o;
  }
}

// ======================= GEMM2: C(f32) = A · Bt^T ==========================
// tile 256x128, BK=32, 4 waves (2M x 2N), per-wave 128x64. LDS 48KB ->
// 2 blocks/CU (two independent barrier domains). 1 barrier + 1 vmcnt/K-tile.
// LDS (ushort): A[2][8192] @0 ; B[2][4096] @16384.
#define G2T(BI, tt)                                                           \
  {                                                                           \
    _Pragma("unroll") for (int m = 0; m < 4; ++m) ra[m] =                     \
        *(const bf16x8*)(Lb + (BI)*16384 + m * 1024 + aoff);                  \
    _Pragma("unroll") for (int n = 0; n < 4; ++n) rb[n] =                     \
        *(const bf16x8*)(Lb + 32768 + (BI)*8192 + n * 1024 + boff);           \
    _Pragma("unroll") for (int m = 4; m < 8; ++m) ra[m] =                     \
        *(const bf16x8*)(Lb + (BI)*16384 + m * 1024 + aoff);                  \
    SB0();                                                                    \
    if ((tt) + 1 < NT) {                                                      \
      unsigned short* dA = L + (((BI) ^ 1) * 8192) + wid * 2048;              \
      unsigned short* dB = L + 16384 + (((BI) ^ 1) * 4096) + wid * 1024;      \
      _Pragma("unroll") for (int i = 0; i < 4; ++i)                           \
          GLOAD_LDS16(pA + i * s16, dA + i * 512);                            \
      _Pragma("unroll") for (int i = 0; i < 2; ++i)                           \
          GLOAD_LDS16(pB + i * s16, dB + i * 512);                            \
    }                                                                         \
    SB0();                                                                    \
    LGKM(4);                                                                  \
    PRIO1();                                                                  \
    _Pragma("unroll") for (int m = 0; m < 4; ++m)                             \
        _Pragma("unroll") for (int n = 0; n < 4; ++n) acc[m][n] =             \
            MFMA_BF16(ra[m], rb[n], acc[m][n], 0, 0, 0);                      \
    PRIO0();                                                                  \
    SB0();                                                                    \
    LGKM(0);                                                                  \
    PRIO1();                                                                  \
    _Pragma("unroll") for (int m = 4; m < 8; ++m)                             \
        _Pragma("unroll") for (int n = 0; n < 4; ++n) acc[m][n] =             \
            MFMA_BF16(ra[m], rb[n], acc[m][n], 0, 0, 0);                      \
    PRIO0();                                                                  \
    VMCNT0();                                                                 \
    BAR();                                                                    \
    pA += 64;                                                                 \
    pB += 64;                                                                 \
  }

__launch_bounds__(256, 2)
__global__ void gemm2_tlp(const unsigned short* __restrict__ A,
                          const unsigned short* __restrict__ Bt,
                          float* __restrict__ C, int M, int N, int K) {
  __shared__ __align__(16) unsigned short L[24576];  // 48 KB
  const int tid = threadIdx.x, lane = tid & 63, wid = tid >> 6;  // 4 waves
  const int wr = wid >> 1, wc = wid & 1;

  const int nby = M >> 8;  // 32
  const int cpx = (int)gridDim.x >> 3;
  const int swz = ((int)blockIdx.x & 7) * cpx + ((int)blockIdx.x >> 3);
  const int bm = (swz % nby) << 8;  // column-major: chunk shares B panel
  const int bn = (swz / nby) << 7;
  const int NT = K >> 5;

  // read offsets (bytes): row 64B, slot ^= (row>>1)&3  (2-way, free)
  const int lp =
      (lane & 15) * 64 + ((((lane >> 4) ^ ((lane >> 1) & 3))) << 4);
  const int aoff = wr * 8192 + lp;
  const int boff = wc * 4096 + lp;

  // stage source (inverse swizzle folded into global col)
  const int colb = (((lane & 3) ^ ((lane >> 3) & 3)) << 4);
  const char* pA =
      (const char*)A + (size_t)(bm + wid * 64 + (lane >> 2)) * K * 2 + colb;
  const char* pB =
      (const char*)Bt + (size_t)(bn + wid * 32 + (lane >> 2)) * K * 2 + colb;
  const size_t s16 = (size_t)K * 32;  // 16 rows (bytes)
  const char* Lb = (const char*)L;

  {  // prologue: stage tile 0 -> buf0
    unsigned short* dA = L + wid * 2048;
    unsigned short* dB = L + 16384 + wid * 1024;
#pragma unroll
    for (int i = 0; i < 4; ++i) GLOAD_LDS16(pA + i * s16, dA + i * 512);
#pragma unroll
    for (int i = 0; i < 2; ++i) GLOAD_LDS16(pB + i * s16, dB + i * 512);
  }
  pA += 64;
  pB += 64;

  f32x4 acc[8][4];
#pragma unroll
  for (int m = 0; m < 8; ++m)
#pragma unroll
    for (int n = 0; n < 4; ++n) acc[m][n] = (f32x4)0.0f;
  bf16x8 ra[8], rb[4];

  VMCNT0();
  BAR();

  for (int t = 0; t < NT; t += 2) {
    G2T(0, t)
    G2T(1, t + 1)
  }

  const int er = (lane >> 4) << 2;
  const int ec = lane & 15;
#pragma unroll
  for (int mi = 0; mi < 8; ++mi)
#pragma unroll
    for (int n = 0; n < 4; ++n)
#pragma unroll
      for (int r = 0; r < 4; ++r) {
        size_t row = (size_t)(bm + wr * 128 + mi * 16 + er + r);
        size_t col = (size_t)(bn + wc * 64 + n * 16 + ec);
        C[row * N + col] = acc[mi][n][r];
      }
}

// ======================= GEMM1: dual-B + silu fuse =========================
// tile 128x128, BK=32, 4 waves (2M x 2N), per-wave 64x64 dual. LDS 48KB ->
// 2 blocks/CU. LDS (ushort): A[2][4096]@0, B1[2][4096]@8192, B3[2][4096]@16384.
#define G1T(BI, tt)                                                           \
  {                                                                           \
    _Pragma("unroll") for (int m = 0; m < 4; ++m) ra[m] =                     \
        *(const bf16x8*)(Lb + (BI)*8192 + m * 1024 + aoff);                   \
    _Pragma("unroll") for (int n = 0; n < 4; ++n) rb1[n] =                    \
        *(const bf16x8*)(Lb + 16384 + (BI)*8192 + n * 1024 + boff);           \
    _Pragma("unroll") for (int n = 0; n < 4; ++n) rb3[n] =                    \
        *(const bf16x8*)(Lb + 32768 + (BI)*8192 + n * 1024 + boff);           \
    SB0();                                                                    \
    if ((tt) + 1 < NT) {                                                      \
      unsigned short* dA = L + (((BI) ^ 1) * 4096) + wid * 1024;              \
      unsigned short* dB1 = L + 8192 + (((BI) ^ 1) * 4096) + wid * 1024;      \
      unsigned short* dB3 = L + 16384 + (((BI) ^ 1) * 4096) + wid * 1024;     \
      _Pragma("unroll") for (int i = 0; i < 2; ++i) {                         \
        GLOAD_LDS16(pA + i * s16, dA + i * 512);                              \
        GLOAD_LDS16(pB1 + i * s16, dB1 + i * 512);                            \
        GLOAD_LDS16(pB3 + i * s16, dB3 + i * 512);                            \
      }                                                                       \
    }                                                                         \
    SB0();                                                                    \
    LGKM(4);                                                                  \
    PRIO1();                                                                  \
    _Pragma("unroll") for (int m = 0; m < 4; ++m)                             \
        _Pragma("unroll") for (int n = 0; n < 4; ++n) accG[m][n] =            \
            MFMA_BF16(ra[m], rb1[n], accG[m][n], 0, 0, 0);                    \
    PRIO0();                                                                  \
    SB0();                                                                    \
    LGKM(0);                                                                  \
    PRIO1();                                                                  \
    _Pragma("unroll") for (int m = 0; m < 4; ++m)                             \
        _Pragma("unroll") for (int n = 0; n < 4; ++n) accL[m][n] =            \
            MFMA_BF16(ra[m], rb3[n], accL[m][n], 0, 0, 0);                    \
    PRIO0();                                                                  \
    VMCNT0();                                                                 \
    BAR();                                                                    \
    pA += 64;                                                                 \
    pB1 += 64;                                                                \
    pB3 += 64;                                                                \
  }

__launch_bounds__(256, 2)
__global__ void gemm1_tlp(const unsigned short* __restrict__ A,
                          const unsigned short* __restrict__ B1p,
                          const unsigned short* __restrict__ B3p,
                          unsigned short* __restrict__ Hout, int M, int N,
                          int K) {
  __shared__ __align__(16) unsigned short L[24576];  // 48 KB
  const int tid = threadIdx.x, lane = tid & 63, wid = tid >> 6;
  const int wr = wid >> 1, wc = wid & 1;

  const int nby = M >> 7;  // 64
  const int cpx = (int)gridDim.x >> 3;
  const int swz = ((int)blockIdx.x & 7) * cpx + ((int)blockIdx.x >> 3);
  const int bm = (swz % nby) << 7;  // column-major: chunk shares B panels
  const int bn = (swz / nby) << 7;
  const int NT = K >> 5;

  const int lp =
      (lane & 15) * 64 + ((((lane >> 4) ^ ((lane >> 1) & 3))) << 4);
  const int aoff = wr * 4096 + lp;
  const int boff = wc * 4096 + lp;

  const int colb = (((lane & 3) ^ ((lane >> 3) & 3)) << 4);
  const char* pA =
      (const char*)A + (size_t)(bm + wid * 32 + (lane >> 2)) * K * 2 + colb;
  const char* pB1 =
      (const char*)B1p + (size_t)(bn + wid * 32 + (lane >> 2)) * K * 2 + colb;
  const char* pB3 =
      (const char*)B3p + (size_t)(bn + wid * 32 + (lane >> 2)) * K * 2 + colb;
  const size_t s16 = (size_t)K * 32;
  const char* Lb = (const char*)L;

  {  // prologue
    unsigned short* dA = L + wid * 1024;
    unsigned short* dB1 = L + 8192 + wid * 1024;
    unsigned short* dB3 = L + 16384 + wid * 1024;
#pragma unroll
    for (int i = 0; i < 2; ++i) {
      GLOAD_LDS16(pA + i * s16, dA + i * 512);
      GLOAD_LDS16(pB1 + i * s16, dB1 + i * 512);
      GLOAD_LDS16(pB3 + i * s16, dB3 + i * 512);
    }
  }
  pA += 64;
  pB1 += 64;
  pB3 += 64;

  f32x4 accG[4][4], accL[4][4];
#pragma unroll
  for (int m = 0; m < 4; ++m)
#pragma unroll
    for (int n = 0; n < 4; ++n) {
      accG[m][n] = (f32x4)0.0f;
      accL[m][n] = (f32x4)0.0f;
    }
  bf16x8 ra[4], rb1[4], rb3[4];

  VMCNT0();
  BAR();

  for (int t = 0; t < NT; t += 2) {
    G1T(0, t)
    G1T(1, t + 1)
  }

  const int er = (lane >> 4) << 2;
  const int ec = lane & 15;
#pragma unroll
  for (int m = 0; m < 4; ++m)
#pragma unroll
    for (int n = 0; n < 4; ++n)
#pragma unroll
      for (int r = 0; r < 4; ++r) {
        float g = accG[m][n][r];
        float li = accL[m][n][r];
        float h = (g / (1.0f + __expf(-g))) * li;
        size_t row = (size_t)(bm + wr * 64 + m * 16 + er + r);
        size_t col = (size_t)(bn + wc * 64 + n * 16 + ec);
        Hout[row * N + col] = f32_to_bf16(h);
      }
}

extern "C" void kernel_launch(void* const* d_in, const int* in_sizes, int n_in,
                              void* d_out, int out_size, void* d_ws,
                              size_t ws_size, hipStream_t stream) {
  const float* x = (const float*)d_in[0];   // (4,2048,2048)
  const float* W1 = (const float*)d_in[1];  // (8192,2048)
  const float* W2 = (const float*)d_in[2];  // (2048,8192)
  const float* W3 = (const float*)d_in[3];  // (8192,2048)
  float* out = (float*)d_out;

  const int M = 8192, D = 2048, H = 8192;
  const size_t NE = (size_t)16777216;

  unsigned short* xb = (unsigned short*)d_ws;
  unsigned short* w1b = xb + NE;
  unsigned short* w3b = w1b + NE;
  unsigned short* w2f = w3b + NE;
  unsigned short* hid = w2f + NE;  // M x H bf16

  conv_f32_bf16<<<2048, 256, 0, stream>>>(x, xb, (int)(NE / 4));
  conv_f32_bf16<<<2048, 256, 0, stream>>>(W1, w1b, (int)(NE / 4));
  conv_f32_bf16<<<2048, 256, 0, stream>>>(W3, w3b, (int)(NE / 4));
  fwht_rows_bf16<<<2048, 256, 0, stream>>>(W2, w2f);

  gemm1_tlp<<<(M / 128) * (H / 128), 256, 0, stream>>>(xb, w1b, w3b, hid, M,
                                                       H, D);
  gemm2_tlp<<<(M / 256) * (D / 128), 256, 0, stream>>>(hid, w2f, out, M, D,
                                                       H);
}